// Round 11
// baseline (134.162 us; speedup 1.0000x reference)
//
#include <hip/hip_runtime.h>

// RetinaNet post-processor, MI355X. Round 11 — single fused kernel.
// N=2, A=9, C=80, H=100, W=152. PRE_NMS_TOP_N=1000, POST_TOP_N=100.
//
//  One kernel, grid (334, 2) x 256 thr, three phases chained by device-scope
//  done-counters (R10's validated ticket pattern):
//   P1 scan:  block b scans chunk b (32 float4/thread, 2x16 batches).
//             Candidates: logits > 3.65 (~711/image, 17-sigma inside
//             [256,1024]) -> u64 key (sigmoid_bits<<32 | ~idx) == jax top_k
//             stable order. LDS-staged, 1 global atomic/block. Ticket sdone.
//   P2 rank:  blocks 0..31 of each image spin (leader-only, acquire) until
//             sdone[n]==334, then rank 32 keys each (8 thr/key x 128 LDS
//             compares), decode rank<256 -> dec. Ticket rdone.
//   P3 nms:   32nd rank block runs single-wave register NMS (early-exit at
//             100 keeps) + emit.
//  Fallback (countA out of [256,1024] or keeps<100; never taken for bench):
//  last block rebuilds exact top-1000 from cls using GLOBAL scratch (keeps
//  static LDS at ~23KB -> 6 blocks/CU co-residency; only 64 blocks ever spin
//  while capacity >= 256, so scan always progresses -> deadlock-free).

#define W_    152
#define H_    100
#define A_    9
#define C_    80
#define HW_   (H_*W_)            // 15200
#define PER_IMG  (A_*C_*HW_)     // 10944000
#define PER_IMG4 (PER_IMG/4)     // 2736000
#define NBIN  2048
#define BIGA_CAP 4096
#define SORTN 2048
#define FASTN 1024
#define NDEC  256
#define THRB 2.0f
#define THRA 3.65f
#define CLIPV 4.135166556742356f  // log(1000/16)

#define TPB      256
#define F4_BATCH 16
#define NBATCH   2
#define CHUNK    (TPB*F4_BATCH*NBATCH)                // 8192 float4
#define NB_SCAN  ((PER_IMG4 + CHUNK - 1) / CHUNK)     // 334
#define LCAPA 64

// ws layout (bytes):
#define OFF_CNTA  0                                // 2 u32
#define OFF_SDONE 8                                // 2 u32
#define OFF_RDONE 16                               // 2 u32
#define OFF_DEC   256                              // 2 x 3*256 x float4
#define OFF_BIGA  (256 + 24576)                    // 2 x 4096 x u64
#define OFF_GSKEY (OFF_BIGA + 65536)               // 2 x 2048 x u64
#define OFF_GHIST (OFF_GSKEY + 32768)              // 2 x 2048 x u32
#define OFF_GFB   (OFF_GHIST + 16384)              // 2 x 3000 x float4

typedef unsigned long long u64;

// Decode one box:
//  o0 = offset box, o1 = plain clipped box, o2 = {area, score(valid?sc:-1), label, 0}
__device__ __forceinline__ void decode_box(
    int idx, float sc, int n,
    const float* __restrict__ reg, const float* __restrict__ anchors,
    float4& o0, float4& o1, float4& o2) {
  int c   = idx % C_;
  int loc = idx / C_;
  int a   = loc % A_;
  int hw  = loc / A_;
  int hh  = hw / W_;
  int ww  = hw - hh * W_;
  int rb  = ((n * A_ + a) * 4) * HW_ + hh * W_ + ww;
  float r0 = reg[rb], r1 = reg[rb + HW_], r2 = reg[rb + 2*HW_], r3 = reg[rb + 3*HW_];
  float4 an = reinterpret_cast<const float4*>(anchors)[loc];
  float wdt = an.z - an.x + 1.0f, hgt = an.w - an.y + 1.0f;
  float cx  = an.x + 0.5f * wdt, cy = an.y + 0.5f * hgt;
  float dx = r0 / 10.0f, dy = r1 / 10.0f;
  float dw = fminf(r2 / 5.0f, CLIPV), dh = fminf(r3 / 5.0f, CLIPV);
  float pcx = dx * wdt + cx, pcy = dy * hgt + cy;
  float pw = expf(dw) * wdt, ph = expf(dh) * hgt;
  float x1 = pcx - 0.5f * pw, y1 = pcy - 0.5f * ph;
  float x2 = pcx + 0.5f * pw - 1.0f, y2 = pcy + 0.5f * ph - 1.0f;
  x1 = fminf(fmaxf(x1, 0.0f), (float)(W_*8) - 1.0f);
  y1 = fminf(fmaxf(y1, 0.0f), (float)(H_*8) - 1.0f);
  x2 = fminf(fmaxf(x2, 0.0f), (float)(W_*8) - 1.0f);
  y2 = fminf(fmaxf(y2, 0.0f), (float)(H_*8) - 1.0f);
  bool valid = sc > 0.0f;
  if ((x2 - x1 + 1.0f < 0.0f) || (y2 - y1 + 1.0f < 0.0f)) valid = false;
  int   label = c + 1;
  float off = (float)label * 4096.0f;
  // offset boxes in f32 (replicates reference rounding at large magnitude)
  float ox1 = x1 + off, oy1 = y1 + off, ox2 = x2 + off, oy2 = y2 + off;
  o0 = make_float4(ox1, oy1, ox2, oy2);
  o1 = make_float4(x1, y1, x2, y2);
  o2 = make_float4((ox2 - ox1 + 1.0f) * (oy2 - oy1 + 1.0f),
                   valid ? sc : -1.0f, (float)label, 0.0f);
}

__global__ __launch_bounds__(TPB) void fused_kernel(
    const float* __restrict__ cls,
    const float* __restrict__ reg,
    const float* __restrict__ anchors,
    unsigned int* __restrict__ cntA,
    unsigned int* __restrict__ sdone,
    unsigned int* __restrict__ rdone,
    u64* __restrict__ bigA,
    float4* __restrict__ dec,
    u64* __restrict__ g_skey,
    unsigned int* __restrict__ g_hist,
    float4* __restrict__ g_fb,
    float* __restrict__ out) {
  const int n = blockIdx.y;
  const int b = blockIdx.x;
  const int tid = threadIdx.x;
  const int lane = tid & 63;

  __shared__ u64 skl[FASTN];            // 8KB  (rank)
  __shared__ float4 dall[3 * NDEC];     // 12KB (nms)
  __shared__ u64 lkA[LCAPA];            // 512B (scan)
  __shared__ unsigned int lcntA, lbaseA;
  __shared__ int s_last, s_fb, s_k, s_cut, s_cnt;
  __shared__ int keptidx[100];
  __shared__ unsigned int csum[256];    // 1KB (fallback)
  __shared__ unsigned char skeep[1000]; // 1KB (fallback)

  // ======================= P1: scan chunk b ================================
  if (tid == 0) lcntA = 0;
  __syncthreads();
  {
    const float4* __restrict__ in = reinterpret_cast<const float4*>(cls) + (size_t)n * PER_IMG4;
#pragma unroll
    for (int half = 0; half < NBATCH; ++half) {
      const int hbase = b * CHUNK + half * (TPB * F4_BATCH) + tid;
      float4 v[F4_BATCH];
#pragma unroll
      for (int j = 0; j < F4_BATCH; ++j) {
        const int t = hbase + j * TPB;
        v[j] = (t < PER_IMG4) ? in[t]
                              : make_float4(-100.f, -100.f, -100.f, -100.f);
      }
#pragma unroll
      for (int j = 0; j < F4_BATCH; ++j) {
        const float4 vv = v[j];
        const float mx = fmaxf(fmaxf(vv.x, vv.y), fmaxf(vv.z, vv.w));
        if (mx > THRA) {
          // very rare path (~0.03% of quads)
          const int f0  = (hbase + j * TPB) * 4;
          const int ac  = f0 / HW_;
          const int rem = f0 - ac * HW_;
          const int h   = rem / W_;
          const int w0  = rem - h * W_;
          const int a   = ac / C_;
          const int c   = ac - a * C_;
          const int idx0 = ((h * W_ + w0) * A_ + a) * C_ + c;   // +720 per elem
          const float xs[4] = {vv.x, vv.y, vv.z, vv.w};
#pragma unroll
          for (int e = 0; e < 4; ++e) {
            const float x = xs[e];
            if (x > THRA) {
              float s = 1.0f / (1.0f + expf(-x));
              unsigned pa = atomicAdd(&lcntA, 1u);
              if (pa < LCAPA)
                lkA[pa] = ((u64)__float_as_uint(s) << 32) |
                          (u64)(0xFFFFFFFFu - (unsigned)(idx0 + e * 720));
            }
          }
        }
      }
    }
  }
  __syncthreads();
  if (tid == 0) {
    unsigned cA = lcntA; if (cA > LCAPA) cA = LCAPA;
    lbaseA = cA ? atomicAdd(&cntA[n], cA) : 0u;
    lcntA = cA;
  }
  __syncthreads();
  if (tid < lcntA) {
    unsigned pos = lbaseA + tid;
    if (pos < BIGA_CAP)
      bigA[(size_t)n * BIGA_CAP + pos] = lkA[tid];
  }
  __threadfence();                    // release bigA/cntA writes
  if (tid == 0) atomicAdd(&sdone[n], 1u);
  if (b >= 32) return;

  // ======================= P2: wait + rank =================================
  if (tid == 0) {
    while (__hip_atomic_load(&sdone[n], __ATOMIC_ACQUIRE,
                             __HIP_MEMORY_SCOPE_AGENT) < (unsigned)NB_SCAN) {
      __builtin_amdgcn_s_sleep(8);
    }
  }
  __syncthreads();
  __threadfence();                    // acquire for all lanes

  const int caRaw = (int)cntA[n];
  int ca = caRaw; if (ca > FASTN) ca = FASTN;
#pragma unroll
  for (int r = 0; r < 4; ++r) {
    int j = tid + r * 256;
    skl[j] = (j < ca) ? bigA[(size_t)n * BIGA_CAP + j] : 0ull;
  }
  __syncthreads();

  const int kidx = b * 32 + (tid >> 3);
  const int sub  = tid & 7;
  const u64 ki = skl[kidx];
  int rank = 0;
#pragma unroll 8
  for (int it = 0; it < 128; ++it) {
    int j = sub + it * 8;             // stride-8: distinct banks
    u64 kj = skl[j];
    rank += (int)((kj > ki) | ((kj == ki) & (j < kidx)));
  }
  rank += __shfl_xor(rank, 1);
  rank += __shfl_xor(rank, 2);
  rank += __shfl_xor(rank, 4);
  if (sub == 0 && rank < NDEC && ki != 0ull) {
    int idx = (int)(0xFFFFFFFFu - (unsigned)(ki & 0xFFFFFFFFu));
    float sc = __uint_as_float((unsigned)(ki >> 32));
    float4 o0, o1, o2;
    decode_box(idx, sc, n, reg, anchors, o0, o1, o2);
    float4* d = dec + (size_t)n * (3 * NDEC);
    d[rank]            = o0;
    d[NDEC + rank]     = o1;
    d[2 * NDEC + rank] = o2;
  }
  __threadfence();                    // release dec writes
  if (tid == 0) s_last = (atomicAdd(&rdone[n], 1u) == 31u) ? 1 : 0;
  __syncthreads();
  if (!s_last) return;
  __threadfence();                    // acquire dec

  // ======================= P3: NMS + emit ==================================
  if (tid == 0) { s_cnt = 0; s_fb = (caRaw > FASTN || caRaw < NDEC) ? 1 : 0; }
  if (caRaw >= NDEC && caRaw <= FASTN) {
#pragma unroll
    for (int r = 0; r < 3; ++r)
      dall[tid + r * 256] = dec[(size_t)n * (3 * NDEC) + tid + r * 256];
  }
  __syncthreads();

  float4* d0 = dall;
  float4* d1 = dall + NDEC;
  float4* d2 = dall + 2 * NDEC;

  if (s_fb == 0) {
    if (tid < 64) {
      float ka_x1 = 0, ka_y1 = 0, ka_x2 = 0, ka_y2 = 0, ka_ar = 0;
      float kb_x1 = 0, kb_y1 = 0, kb_x2 = 0, kb_y2 = 0, kb_ar = 0;
      int k = 0;
      for (int i = 0; i < NDEC; ++i) {
        if (k >= 100) break;
        float4 bx = d0[i];
        float4 ai = d2[i];
        float x1 = bx.x, y1 = bx.y, x2 = bx.z, y2 = bx.w, ar = ai.x, sc = ai.y;
        bool sup = false;
        if (lane < k) {
          float iw = fminf(x2, ka_x2) - fmaxf(x1, ka_x1) + 1.0f;
          float ih = fminf(y2, ka_y2) - fmaxf(y1, ka_y1) + 1.0f;
          if (iw > 0.0f && ih > 0.0f) {
            float inter = iw * ih;
            sup = inter / (ar + ka_ar - inter) > 0.5f;
          }
        }
        if (lane + 64 < k) {
          float iw = fminf(x2, kb_x2) - fmaxf(x1, kb_x1) + 1.0f;
          float ih = fminf(y2, kb_y2) - fmaxf(y1, kb_y1) + 1.0f;
          if (iw > 0.0f && ih > 0.0f) {
            float inter = iw * ih;
            sup = sup || (inter / (ar + kb_ar - inter) > 0.5f);
          }
        }
        bool any = __any(sup);
        if ((sc > 0.0f) && !any) {
          if (lane == k)      { ka_x1 = x1; ka_y1 = y1; ka_x2 = x2; ka_y2 = y2; ka_ar = ar; }
          if (lane == k - 64) { kb_x1 = x1; kb_y1 = y1; kb_x2 = x2; kb_y2 = y2; kb_ar = ar; }
          if (lane == 0) keptidx[k] = i;
          ++k;
        }
      }
      if (lane == 0) {
        s_k = k;
        if (k < 100) s_fb = 1;
      }
    }
    __syncthreads();

    if (s_fb == 0) {
      if (tid < 100) {
        int f = keptidx[tid];
        float4 bb = d1[f];
        float4 ai = d2[f];
        int ob = (n * 100 + tid) * 4;
        out[ob + 0] = bb.x; out[ob + 1] = bb.y; out[ob + 2] = bb.z; out[ob + 3] = bb.w;
        out[800  + n * 100 + tid] = ai.y;
        out[1000 + n * 100 + tid] = ai.z;
      }
      return;
    }
  }
  __syncthreads();

  // ======= fallback: rebuild exact top-1000 from cls (never taken; ========
  // ======= uses GLOBAL scratch to keep static LDS small)           ========
  unsigned int* hist = g_hist + n * NBIN;
  u64*  skey = g_skey + n * SORTN;
  float4* fb0 = g_fb + (size_t)n * 3000;
  float4* fb1 = fb0 + 1000;
  float4* fb2 = fb0 + 2000;
  for (int i = tid; i < NBIN; i += 256) hist[i] = 0;
  __syncthreads();
  __threadfence();
  const float* __restrict__ cn = cls + (size_t)n * PER_IMG;
  for (int e = tid; e < PER_IMG; e += 256) {
    float x = cn[e];
    if (x > THRB) {
      int bb = (int)((x - THRB) * 256.0f); if (bb > NBIN - 1) bb = NBIN - 1;
      atomicAdd(&hist[bb], 1u);
    }
  }
  __syncthreads();
  __threadfence();
  {
    unsigned int s = 0;
    for (int bb = tid * 8; bb < tid * 8 + 8; ++bb) s += hist[bb];
    csum[tid] = s;
  }
  __syncthreads();
  if (tid == 0) {
    int acc = 0, cut = 0;
    for (int cch = 255; cch >= 0; --cch) {
      int nacc = acc + (int)csum[cch];
      if (nacc >= 1000) {
        int aa = acc;
        for (int bb = cch * 8 + 7; bb >= cch * 8; --bb) { aa += (int)hist[bb]; if (aa >= 1000) { cut = bb; break; } }
        break;
      }
      acc = nacc;
    }
    s_cut = cut;
  }
  __syncthreads();
  const int cut = s_cut;
  for (int e = tid; e < PER_IMG; e += 256) {
    float x = cn[e];
    if (x > THRB) {
      int bb = (int)((x - THRB) * 256.0f); if (bb > NBIN - 1) bb = NBIN - 1;
      if (bb >= cut) {
        int ac2 = e / HW_;
        int rem = e - ac2 * HW_;
        int hh  = rem / W_;
        int ww  = rem - hh * W_;
        int a2  = ac2 / C_;
        int c2  = ac2 - a2 * C_;
        int jidx = ((hh * W_ + ww) * A_ + a2) * C_ + c2;
        float s = 1.0f / (1.0f + expf(-x));
        int pos = atomicAdd(&s_cnt, 1);
        if (pos < SORTN)
          skey[pos] = ((u64)__float_as_uint(s) << 32) |
                      (u64)(0xFFFFFFFFu - (unsigned)jidx);
      }
    }
  }
  __syncthreads();
  __threadfence();
  int cnt = s_cnt; if (cnt > SORTN) cnt = SORTN;
  for (int p = tid; p < SORTN; p += 256)
    if (p >= cnt) skey[p] = 0ull;
  __syncthreads();
  __threadfence();
  for (int k = 2; k <= SORTN; k <<= 1) {
    for (int j = k >> 1; j > 0; j >>= 1) {
#pragma unroll
      for (int u = 0; u < 8; ++u) {
        int tt = tid + u * 256;
        int ixj = tt ^ j;
        if (ixj > tt) {
          u64 va = skey[tt], vb = skey[ixj];
          bool asc = ((tt & k) == 0);
          if (asc ? (va > vb) : (va < vb)) { skey[tt] = vb; skey[ixj] = va; }
        }
      }
      __syncthreads();
      __threadfence();
    }
  }
  for (int i = tid; i < 1000; i += 256) {
    u64 key = skey[SORTN - 1 - i];
    bool ok = (i < cnt) && (key != 0ull);
    int   idx = ok ? (int)(0xFFFFFFFFu - (unsigned)(key & 0xFFFFFFFFu)) : 0;
    float sc  = ok ? __uint_as_float((unsigned)(key >> 32)) : -1.0f;
    float4 o0, o1, o2;
    decode_box(idx, sc, n, reg, anchors, o0, o1, o2);
    fb0[i] = o0; fb1[i] = o1; fb2[i] = o2;
  }
  __syncthreads();
  __threadfence();
  if (tid < 64) {
    float ka_x1 = 0, ka_y1 = 0, ka_x2 = 0, ka_y2 = 0, ka_ar = 0;
    float kb_x1 = 0, kb_y1 = 0, kb_x2 = 0, kb_y2 = 0, kb_ar = 0;
    int k = 0;
    for (int i = 0; i < 1000; ++i) {
      if (k >= 100) break;
      float4 bx = fb0[i];
      float4 ai = fb2[i];
      float x1 = bx.x, y1 = bx.y, x2 = bx.z, y2 = bx.w, ar = ai.x, sc = ai.y;
      bool sup = false;
      if (lane < k) {
        float iw = fminf(x2, ka_x2) - fmaxf(x1, ka_x1) + 1.0f;
        float ih = fminf(y2, ka_y2) - fmaxf(y1, ka_y1) + 1.0f;
        if (iw > 0.0f && ih > 0.0f) {
          float inter = iw * ih;
          sup = inter / (ar + ka_ar - inter) > 0.5f;
        }
      }
      if (lane + 64 < k) {
        float iw = fminf(x2, kb_x2) - fmaxf(x1, kb_x1) + 1.0f;
        float ih = fminf(y2, kb_y2) - fmaxf(y1, kb_y1) + 1.0f;
        if (iw > 0.0f && ih > 0.0f) {
          float inter = iw * ih;
          sup = sup || (inter / (ar + kb_ar - inter) > 0.5f);
        }
      }
      bool any = __any(sup);
      bool valid = sc > 0.0f;
      if (valid && !any) {
        if (lane == k)      { ka_x1 = x1; ka_y1 = y1; ka_x2 = x2; ka_y2 = y2; ka_ar = ar; }
        if (lane == k - 64) { kb_x1 = x1; kb_y1 = y1; kb_x2 = x2; kb_y2 = y2; kb_ar = ar; }
        if (lane == 0) { keptidx[k] = i; skeep[i] = 1; }
        ++k;
      } else if (lane == 0) {
        skeep[i] = 0;
      }
    }
    if (lane == 0) {
      if (k < 100) {
        int fill = k;
        for (int q = 0; q < 1000 && fill < 100; ++q)
          if (!skeep[q]) keptidx[fill++] = q;
      }
      s_k = k;
    }
  }
  __syncthreads();
  if (tid < 100) {
    int f = keptidx[tid];
    bool isk = tid < s_k;
    float4 bb = fb1[f];
    float sc  = isk ? fb2[f].y : -1.0f;
    float lab = (sc > 0.0f) ? fb2[f].z : 0.0f;
    int ob = (n * 100 + tid) * 4;
    out[ob + 0] = bb.x; out[ob + 1] = bb.y; out[ob + 2] = bb.z; out[ob + 3] = bb.w;
    out[800  + n * 100 + tid] = sc;
    out[1000 + n * 100 + tid] = lab;
  }
}

extern "C" void kernel_launch(void* const* d_in, const int* in_sizes, int n_in,
                              void* d_out, int out_size, void* d_ws, size_t ws_size,
                              hipStream_t stream) {
  const float* cls = (const float*)d_in[0];
  const float* reg = (const float*)d_in[1];
  const float* anc = (const float*)d_in[2];
  float* out = (float*)d_out;
  char* ws = (char*)d_ws;
  unsigned int* cntA  = (unsigned int*)(ws + OFF_CNTA);
  unsigned int* sdone = (unsigned int*)(ws + OFF_SDONE);
  unsigned int* rdone = (unsigned int*)(ws + OFF_RDONE);
  float4* dec         = (float4*)(ws + OFF_DEC);
  u64*    bigA        = (u64*)(ws + OFF_BIGA);
  u64*    g_skey      = (u64*)(ws + OFF_GSKEY);
  unsigned int* g_hist = (unsigned int*)(ws + OFF_GHIST);
  float4* g_fb        = (float4*)(ws + OFF_GFB);

  hipMemsetAsync(d_ws, 0, 24, stream);
  dim3 grid(NB_SCAN, 2);
  fused_kernel<<<grid, TPB, 0, stream>>>(cls, reg, anc, cntA, sdone, rdone,
                                         bigA, dec, g_skey, g_hist, g_fb, out);
}

// Round 12
// 65.766 us; speedup vs baseline: 2.0400x; 2.0400x over previous
//
#include <hip/hip_runtime.h>

// RetinaNet post-processor, MI355X. Round 12 — revert to R10 (best: 65.9us).
// R11's single-kernel fusion regressed (134us): all 668 blocks executed a
// device-scope __threadfence (L2 writeback on non-coherent per-XCD L2s),
// serializing the scan epilogue. Kernel boundaries are the cheaper fence.
//
//  K1 scan:     334 blocks/image x 256 thr, 32 float4/thread (2x16 batches).
//               Emits list A: logits > 3.65 (~711/image, 17-sigma inside
//               [256,1024]) as u64 key (sigmoid_bits<<32 | ~idx) == jax
//               top_k stable order.
//  K2 rank_nms: 32 blocks/image x 256 thr; 8 thr/key x 128 LDS compares ->
//               exact rank; sub==0 decodes rank<256 boxes -> ws. Then
//               threadfence + done[n] ticket; the LAST block per image runs
//               the single-wave register NMS (early-exit at 100 keeps) and
//               emits. Fallback (countA out of [256,1024] or keeps<100):
//               last block recomputes top-1000 directly from cls (hist cutoff
//               + 2048 bitonic + NMS-1000 + padding) -- never taken for the
//               bench input, correctness-only.

#define W_    152
#define H_    100
#define A_    9
#define C_    80
#define HW_   (H_*W_)            // 15200
#define PER_IMG  (A_*C_*HW_)     // 10944000
#define PER_IMG4 (PER_IMG/4)     // 2736000
#define NBIN  2048
#define BIGA_CAP 4096
#define SORTN 2048
#define FASTN 1024
#define NDEC  256
#define THRB 2.0f
#define THRA 3.65f
#define CLIPV 4.135166556742356f  // log(1000/16)

#define TPB      256
#define F4_BATCH 16
#define NBATCH   2
#define CHUNK    (TPB*F4_BATCH*NBATCH)                // 8192 float4
#define NB_SCAN  ((PER_IMG4 + CHUNK - 1) / CHUNK)     // 334
#define LCAPA 64

// ws layout (bytes):
#define OFF_CNTA 0                                 // 2 u32
#define OFF_DONE 8                                 // 2 u32
#define OFF_DEC  256                               // 2 x 3*256 x float4 = 24576
#define OFF_BIGA (256 + 24576)                     // 2 x 4096 x u64 = 64KB

typedef unsigned long long u64;

__global__ __launch_bounds__(TPB) void scan_kernel(
    const float* __restrict__ cls,
    unsigned int* __restrict__ cntA,
    u64* __restrict__ bigA) {
  const int n = blockIdx.y;
  const float4* __restrict__ in = reinterpret_cast<const float4*>(cls) + (size_t)n * PER_IMG4;
  __shared__ unsigned int lcntA, lbaseA;
  __shared__ u64 lkA[LCAPA];
  if (threadIdx.x == 0) lcntA = 0;
  __syncthreads();

#pragma unroll
  for (int half = 0; half < NBATCH; ++half) {
    const int hbase = blockIdx.x * CHUNK + half * (TPB * F4_BATCH) + threadIdx.x;
    float4 v[F4_BATCH];
#pragma unroll
    for (int j = 0; j < F4_BATCH; ++j) {
      const int t = hbase + j * TPB;
      v[j] = (t < PER_IMG4) ? in[t]
                            : make_float4(-100.f, -100.f, -100.f, -100.f);
    }
#pragma unroll
    for (int j = 0; j < F4_BATCH; ++j) {
      const float4 vv = v[j];
      const float mx = fmaxf(fmaxf(vv.x, vv.y), fmaxf(vv.z, vv.w));
      if (mx > THRA) {
        // very rare path (~0.03% of quads): index math + LDS staging
        const int f0  = (hbase + j * TPB) * 4;
        const int ac  = f0 / HW_;
        const int rem = f0 - ac * HW_;
        const int h   = rem / W_;
        const int w0  = rem - h * W_;
        const int a   = ac / C_;
        const int c   = ac - a * C_;
        const int idx0 = ((h * W_ + w0) * A_ + a) * C_ + c;   // +720 per elem
        const float xs[4] = {vv.x, vv.y, vv.z, vv.w};
#pragma unroll
        for (int e = 0; e < 4; ++e) {
          const float x = xs[e];
          if (x > THRA) {
            float s = 1.0f / (1.0f + expf(-x));
            unsigned pa = atomicAdd(&lcntA, 1u);
            if (pa < LCAPA)
              lkA[pa] = ((u64)__float_as_uint(s) << 32) |
                        (u64)(0xFFFFFFFFu - (unsigned)(idx0 + e * 720));
          }
        }
      }
    }
  }
  __syncthreads();
  if (threadIdx.x == 0) {
    unsigned cA = lcntA; if (cA > LCAPA) cA = LCAPA;
    lbaseA = cA ? atomicAdd(&cntA[n], cA) : 0u;
    lcntA = cA;
  }
  __syncthreads();
  if (threadIdx.x < lcntA) {
    unsigned pos = lbaseA + threadIdx.x;
    if (pos < BIGA_CAP)
      bigA[(size_t)n * BIGA_CAP + pos] = lkA[threadIdx.x];
  }
}

// Decode one box:
//  o0 = offset box, o1 = plain clipped box, o2 = {area, score(valid?sc:-1), label, 0}
__device__ __forceinline__ void decode_box(
    int idx, float sc, int n,
    const float* __restrict__ reg, const float* __restrict__ anchors,
    float4& o0, float4& o1, float4& o2) {
  int c   = idx % C_;
  int loc = idx / C_;
  int a   = loc % A_;
  int hw  = loc / A_;
  int hh  = hw / W_;
  int ww  = hw - hh * W_;
  int rb  = ((n * A_ + a) * 4) * HW_ + hh * W_ + ww;
  float r0 = reg[rb], r1 = reg[rb + HW_], r2 = reg[rb + 2*HW_], r3 = reg[rb + 3*HW_];
  float4 an = reinterpret_cast<const float4*>(anchors)[loc];
  float wdt = an.z - an.x + 1.0f, hgt = an.w - an.y + 1.0f;
  float cx  = an.x + 0.5f * wdt, cy = an.y + 0.5f * hgt;
  float dx = r0 / 10.0f, dy = r1 / 10.0f;
  float dw = fminf(r2 / 5.0f, CLIPV), dh = fminf(r3 / 5.0f, CLIPV);
  float pcx = dx * wdt + cx, pcy = dy * hgt + cy;
  float pw = expf(dw) * wdt, ph = expf(dh) * hgt;
  float x1 = pcx - 0.5f * pw, y1 = pcy - 0.5f * ph;
  float x2 = pcx + 0.5f * pw - 1.0f, y2 = pcy + 0.5f * ph - 1.0f;
  x1 = fminf(fmaxf(x1, 0.0f), (float)(W_*8) - 1.0f);
  y1 = fminf(fmaxf(y1, 0.0f), (float)(H_*8) - 1.0f);
  x2 = fminf(fmaxf(x2, 0.0f), (float)(W_*8) - 1.0f);
  y2 = fminf(fmaxf(y2, 0.0f), (float)(H_*8) - 1.0f);
  bool valid = sc > 0.0f;
  if ((x2 - x1 + 1.0f < 0.0f) || (y2 - y1 + 1.0f < 0.0f)) valid = false;
  int   label = c + 1;
  float off = (float)label * 4096.0f;
  // offset boxes in f32 (replicates reference rounding at large magnitude)
  float ox1 = x1 + off, oy1 = y1 + off, ox2 = x2 + off, oy2 = y2 + off;
  o0 = make_float4(ox1, oy1, ox2, oy2);
  o1 = make_float4(x1, y1, x2, y2);
  o2 = make_float4((ox2 - ox1 + 1.0f) * (oy2 - oy1 + 1.0f),
                   valid ? sc : -1.0f, (float)label, 0.0f);
}

// 32 blocks per image; block b ranks keys [b*32, b*32+32), decodes rank<NDEC;
// last-finishing block per image runs NMS + emit (fallback: rebuild from cls).
__global__ __launch_bounds__(256) void rank_nms_kernel(
    const float* __restrict__ cls,
    const unsigned int* __restrict__ cntA,
    const u64* __restrict__ bigA,
    const float* __restrict__ reg, const float* __restrict__ anchors,
    unsigned int* __restrict__ done,
    float4* __restrict__ dec,
    float* __restrict__ out) {
  const int n = blockIdx.x >> 5;
  const int b = blockIdx.x & 31;
  const int tid = threadIdx.x;
  const int lane = tid & 63;

  __shared__ u64 skl[FASTN];
  __shared__ int s_last;
  // finish-phase storage
  __shared__ float4 dall[3 * NDEC];
  __shared__ int s_fb, s_k, s_cut, s_cnt;
  __shared__ int keptidx[100];
  // fallback-only storage
  __shared__ u64 skey[SORTN];
  __shared__ unsigned int shist[NBIN];
  __shared__ unsigned int csum[256];
  __shared__ float4 fb0[1000], fb1[1000], fb2[1000];
  __shared__ unsigned char skeep[1000];

  const int caRaw = (int)cntA[n];
  int ca = caRaw; if (ca > FASTN) ca = FASTN;

  // ---- rank phase ----
#pragma unroll
  for (int r = 0; r < 4; ++r) {
    int j = tid + r * 256;
    skl[j] = (j < ca) ? bigA[(size_t)n * BIGA_CAP + j] : 0ull;
  }
  __syncthreads();

  const int kidx = b * 32 + (tid >> 3);
  const int sub  = tid & 7;
  const u64 ki = skl[kidx];
  int rank = 0;
#pragma unroll 8
  for (int it = 0; it < 128; ++it) {
    int j = sub + it * 8;                 // stride-8: distinct banks
    u64 kj = skl[j];
    rank += (int)((kj > ki) | ((kj == ki) & (j < kidx)));
  }
  rank += __shfl_xor(rank, 1);
  rank += __shfl_xor(rank, 2);
  rank += __shfl_xor(rank, 4);
  if (sub == 0 && rank < NDEC && ki != 0ull) {
    int idx = (int)(0xFFFFFFFFu - (unsigned)(ki & 0xFFFFFFFFu));
    float sc = __uint_as_float((unsigned)(ki >> 32));
    float4 o0, o1, o2;
    decode_box(idx, sc, n, reg, anchors, o0, o1, o2);
    float4* d = dec + (size_t)n * (3 * NDEC);
    d[rank]            = o0;
    d[NDEC + rank]     = o1;
    d[2 * NDEC + rank] = o2;
  }

  // ---- completion ticket: last block of image n continues ----
  __threadfence();
  if (tid == 0) {
    unsigned old = atomicAdd(&done[n], 1u);
    s_last = (old == 31u) ? 1 : 0;
  }
  __syncthreads();
  if (!s_last) return;
  __threadfence();   // acquire: see all blocks' dec writes

  if (tid == 0) { s_cnt = 0; s_fb = (caRaw > FASTN || caRaw < NDEC) ? 1 : 0; }

  // ---- fast path: load pre-decoded boxes ----
  if (caRaw >= NDEC && caRaw <= FASTN) {
#pragma unroll
    for (int r = 0; r < 3; ++r)
      dall[tid + r * 256] = dec[(size_t)n * (3 * NDEC) + tid + r * 256];
  }
  __syncthreads();

  float4* d0 = dall;
  float4* d1 = dall + NDEC;
  float4* d2 = dall + 2 * NDEC;

  if (s_fb == 0) {
    // ---- single-wave NMS over top NDEC, early-exit at 100 keeps ----
    if (tid < 64) {
      float ka_x1 = 0, ka_y1 = 0, ka_x2 = 0, ka_y2 = 0, ka_ar = 0;
      float kb_x1 = 0, kb_y1 = 0, kb_x2 = 0, kb_y2 = 0, kb_ar = 0;
      int k = 0;
      for (int i = 0; i < NDEC; ++i) {
        if (k >= 100) break;
        float4 bx = d0[i];
        float4 ai = d2[i];
        float x1 = bx.x, y1 = bx.y, x2 = bx.z, y2 = bx.w, ar = ai.x, sc = ai.y;
        bool sup = false;
        if (lane < k) {
          float iw = fminf(x2, ka_x2) - fmaxf(x1, ka_x1) + 1.0f;
          float ih = fminf(y2, ka_y2) - fmaxf(y1, ka_y1) + 1.0f;
          if (iw > 0.0f && ih > 0.0f) {
            float inter = iw * ih;
            sup = inter / (ar + ka_ar - inter) > 0.5f;
          }
        }
        if (lane + 64 < k) {
          float iw = fminf(x2, kb_x2) - fmaxf(x1, kb_x1) + 1.0f;
          float ih = fminf(y2, kb_y2) - fmaxf(y1, kb_y1) + 1.0f;
          if (iw > 0.0f && ih > 0.0f) {
            float inter = iw * ih;
            sup = sup || (inter / (ar + kb_ar - inter) > 0.5f);
          }
        }
        bool any = __any(sup);
        if ((sc > 0.0f) && !any) {
          if (lane == k)      { ka_x1 = x1; ka_y1 = y1; ka_x2 = x2; ka_y2 = y2; ka_ar = ar; }
          if (lane == k - 64) { kb_x1 = x1; kb_y1 = y1; kb_x2 = x2; kb_y2 = y2; kb_ar = ar; }
          if (lane == 0) keptidx[k] = i;
          ++k;
        }
      }
      if (lane == 0) {
        s_k = k;
        if (k < 100) s_fb = 1;
      }
    }
    __syncthreads();

    if (s_fb == 0) {
      if (tid < 100) {
        int f = keptidx[tid];
        float4 bb = d1[f];
        float4 ai = d2[f];
        int ob = (n * 100 + tid) * 4;
        out[ob + 0] = bb.x; out[ob + 1] = bb.y; out[ob + 2] = bb.z; out[ob + 3] = bb.w;
        out[800  + n * 100 + tid] = ai.y;
        out[1000 + n * 100 + tid] = ai.z;
      }
      return;
    }
  }
  __syncthreads();

  // ======= fallback: rebuild exact top-1000 from cls (never taken) =========
  for (int i = tid; i < NBIN; i += 256) shist[i] = 0;
  __syncthreads();
  const float* __restrict__ cn = cls + (size_t)n * PER_IMG;
  for (int e = tid; e < PER_IMG; e += 256) {
    float x = cn[e];
    if (x > THRB) {
      int bb = (int)((x - THRB) * 256.0f); if (bb > NBIN - 1) bb = NBIN - 1;
      atomicAdd(&shist[bb], 1u);
    }
  }
  __syncthreads();
  {
    unsigned int s = 0;
    for (int bb = tid * 8; bb < tid * 8 + 8; ++bb) s += shist[bb];
    csum[tid] = s;
  }
  __syncthreads();
  if (tid == 0) {
    int acc = 0, cut = 0;
    for (int cch = 255; cch >= 0; --cch) {
      int nacc = acc + (int)csum[cch];
      if (nacc >= 1000) {
        int aa = acc;
        for (int bb = cch * 8 + 7; bb >= cch * 8; --bb) { aa += (int)shist[bb]; if (aa >= 1000) { cut = bb; break; } }
        break;
      }
      acc = nacc;
    }
    s_cut = cut;
  }
  __syncthreads();
  const int cut = s_cut;
  for (int e = tid; e < PER_IMG; e += 256) {
    float x = cn[e];
    if (x > THRB) {
      int bb = (int)((x - THRB) * 256.0f); if (bb > NBIN - 1) bb = NBIN - 1;
      if (bb >= cut) {
        // jax-order index from memory-order e
        int ac2 = e / HW_;
        int rem = e - ac2 * HW_;
        int hh  = rem / W_;
        int ww  = rem - hh * W_;
        int a2  = ac2 / C_;
        int c2  = ac2 - a2 * C_;
        int jidx = ((hh * W_ + ww) * A_ + a2) * C_ + c2;
        float s = 1.0f / (1.0f + expf(-x));
        int pos = atomicAdd(&s_cnt, 1);
        if (pos < SORTN)
          skey[pos] = ((u64)__float_as_uint(s) << 32) |
                      (u64)(0xFFFFFFFFu - (unsigned)jidx);
      }
    }
  }
  __syncthreads();
  int cnt = s_cnt; if (cnt > SORTN) cnt = SORTN;
  for (int p = tid; p < SORTN; p += 256)
    if (p >= cnt) skey[p] = 0ull;
  __syncthreads();
  for (int k = 2; k <= SORTN; k <<= 1) {
    for (int j = k >> 1; j > 0; j >>= 1) {
#pragma unroll
      for (int u = 0; u < 8; ++u) {
        int tt = tid + u * 256;
        int ixj = tt ^ j;
        if (ixj > tt) {
          u64 va = skey[tt], vb = skey[ixj];
          bool asc = ((tt & k) == 0);
          if (asc ? (va > vb) : (va < vb)) { skey[tt] = vb; skey[ixj] = va; }
        }
      }
      __syncthreads();
    }
  }
  for (int i = tid; i < 1000; i += 256) {
    u64 key = skey[SORTN - 1 - i];
    bool ok = (i < cnt) && (key != 0ull);
    int   idx = ok ? (int)(0xFFFFFFFFu - (unsigned)(key & 0xFFFFFFFFu)) : 0;
    float sc  = ok ? __uint_as_float((unsigned)(key >> 32)) : -1.0f;
    float4 o0, o1, o2;
    decode_box(idx, sc, n, reg, anchors, o0, o1, o2);
    fb0[i] = o0; fb1[i] = o1; fb2[i] = o2;
  }
  __syncthreads();
  if (tid < 64) {
    float ka_x1 = 0, ka_y1 = 0, ka_x2 = 0, ka_y2 = 0, ka_ar = 0;
    float kb_x1 = 0, kb_y1 = 0, kb_x2 = 0, kb_y2 = 0, kb_ar = 0;
    int k = 0;
    for (int i = 0; i < 1000; ++i) {
      if (k >= 100) break;
      float4 bx = fb0[i];
      float4 ai = fb2[i];
      float x1 = bx.x, y1 = bx.y, x2 = bx.z, y2 = bx.w, ar = ai.x, sc = ai.y;
      bool sup = false;
      if (lane < k) {
        float iw = fminf(x2, ka_x2) - fmaxf(x1, ka_x1) + 1.0f;
        float ih = fminf(y2, ka_y2) - fmaxf(y1, ka_y1) + 1.0f;
        if (iw > 0.0f && ih > 0.0f) {
          float inter = iw * ih;
          sup = inter / (ar + ka_ar - inter) > 0.5f;
        }
      }
      if (lane + 64 < k) {
        float iw = fminf(x2, kb_x2) - fmaxf(x1, kb_x1) + 1.0f;
        float ih = fminf(y2, kb_y2) - fmaxf(y1, kb_y1) + 1.0f;
        if (iw > 0.0f && ih > 0.0f) {
          float inter = iw * ih;
          sup = sup || (inter / (ar + kb_ar - inter) > 0.5f);
        }
      }
      bool any = __any(sup);
      bool valid = sc > 0.0f;
      if (valid && !any) {
        if (lane == k)      { ka_x1 = x1; ka_y1 = y1; ka_x2 = x2; ka_y2 = y2; ka_ar = ar; }
        if (lane == k - 64) { kb_x1 = x1; kb_y1 = y1; kb_x2 = x2; kb_y2 = y2; kb_ar = ar; }
        if (lane == 0) { keptidx[k] = i; skeep[i] = 1; }
        ++k;
      } else if (lane == 0) {
        skeep[i] = 0;
      }
    }
    if (lane == 0) {
      if (k < 100) {
        int fill = k;
        for (int q = 0; q < 1000 && fill < 100; ++q)
          if (!skeep[q]) keptidx[fill++] = q;
      }
      s_k = k;
    }
  }
  __syncthreads();
  if (tid < 100) {
    int f = keptidx[tid];
    bool isk = tid < s_k;
    float4 bb = fb1[f];
    float sc  = isk ? fb2[f].y : -1.0f;
    float lab = (sc > 0.0f) ? fb2[f].z : 0.0f;
    int ob = (n * 100 + tid) * 4;
    out[ob + 0] = bb.x; out[ob + 1] = bb.y; out[ob + 2] = bb.z; out[ob + 3] = bb.w;
    out[800  + n * 100 + tid] = sc;
    out[1000 + n * 100 + tid] = lab;
  }
}

extern "C" void kernel_launch(void* const* d_in, const int* in_sizes, int n_in,
                              void* d_out, int out_size, void* d_ws, size_t ws_size,
                              hipStream_t stream) {
  const float* cls = (const float*)d_in[0];
  const float* reg = (const float*)d_in[1];
  const float* anc = (const float*)d_in[2];
  float* out = (float*)d_out;
  char* ws = (char*)d_ws;
  unsigned int* cntA = (unsigned int*)(ws + OFF_CNTA);
  unsigned int* done = (unsigned int*)(ws + OFF_DONE);
  float4* dec        = (float4*)(ws + OFF_DEC);
  u64*    bigA       = (u64*)(ws + OFF_BIGA);

  hipMemsetAsync(d_ws, 0, 16, stream);
  dim3 g1(NB_SCAN, 2);
  scan_kernel<<<g1, TPB, 0, stream>>>(cls, cntA, bigA);
  rank_nms_kernel<<<64, 256, 0, stream>>>(cls, cntA, bigA, reg, anc, done, dec, out);
}